// Round 1
// baseline (263.918 us; speedup 1.0000x reference)
//
#include <hip/hip_runtime.h>

// Fused 3-layer MLP: out = relu(relu(x@W0+b0)@W1+b1)@W2+b2
// x: [N, 128] f32, W0: [128,32], W1: [32,32], W2: [32,16], out: [N,16] f32.
// edge_index / edge_weight are unused (ChebConv K=1 per the reference).
//
// One thread per node. Weights are read with wave-uniform addresses so the
// backend can select scalar (s_load) loads; x is read as float4 (16B/lane).

#define N_IN  128
#define HID   32
#define N_OUT 16

__global__ __launch_bounds__(256) void gnn_mlp_kernel(
    const float* __restrict__ x,
    const float* __restrict__ W0, const float* __restrict__ b0,
    const float* __restrict__ W1, const float* __restrict__ b1,
    const float* __restrict__ W2, const float* __restrict__ b2,
    float* __restrict__ out, int n_nodes)
{
    int n = blockIdx.x * blockDim.x + threadIdx.x;
    if (n >= n_nodes) return;

    const float4* xrow = reinterpret_cast<const float4*>(x + (size_t)n * N_IN);

    // ---- layer 0: h0 = relu(x @ W0 + b0) ----
    float h0[HID];
    #pragma unroll
    for (int j = 0; j < HID; ++j) h0[j] = b0[j];

    #pragma unroll
    for (int k4 = 0; k4 < N_IN / 4; ++k4) {
        float4 xv = xrow[k4];
        const float* w = W0 + (size_t)(k4 * 4) * HID;
        #pragma unroll
        for (int j = 0; j < HID; ++j) {
            float acc = h0[j];
            acc = fmaf(xv.x, w[0 * HID + j], acc);
            acc = fmaf(xv.y, w[1 * HID + j], acc);
            acc = fmaf(xv.z, w[2 * HID + j], acc);
            acc = fmaf(xv.w, w[3 * HID + j], acc);
            h0[j] = acc;
        }
    }
    #pragma unroll
    for (int j = 0; j < HID; ++j) h0[j] = fmaxf(h0[j], 0.0f);

    // ---- layer 1: h1 = relu(h0 @ W1 + b1) ----
    float h1[HID];
    #pragma unroll
    for (int j = 0; j < HID; ++j) h1[j] = b1[j];
    #pragma unroll
    for (int k = 0; k < HID; ++k) {
        #pragma unroll
        for (int j = 0; j < HID; ++j)
            h1[j] = fmaf(h0[k], W1[k * HID + j], h1[j]);
    }
    #pragma unroll
    for (int j = 0; j < HID; ++j) h1[j] = fmaxf(h1[j], 0.0f);

    // ---- layer 2: o = h1 @ W2 + b2 ----
    float o[N_OUT];
    #pragma unroll
    for (int j = 0; j < N_OUT; ++j) o[j] = b2[j];
    #pragma unroll
    for (int k = 0; k < HID; ++k) {
        #pragma unroll
        for (int j = 0; j < N_OUT; ++j)
            o[j] = fmaf(h1[k], W2[k * N_OUT + j], o[j]);
    }

    // ---- coalesced-ish float4 store of the 16 outputs ----
    float4* orow = reinterpret_cast<float4*>(out + (size_t)n * N_OUT);
    #pragma unroll
    for (int q = 0; q < N_OUT / 4; ++q)
        orow[q] = make_float4(o[4 * q + 0], o[4 * q + 1], o[4 * q + 2], o[4 * q + 3]);
}

extern "C" void kernel_launch(void* const* d_in, const int* in_sizes, int n_in,
                              void* d_out, int out_size, void* d_ws, size_t ws_size,
                              hipStream_t stream) {
    // setup_inputs() order: x, edge_index, edge_weight, W0, b0, W1, b1, W2, b2
    const float* x  = (const float*)d_in[0];
    // d_in[1] = edge_index (int64, unused), d_in[2] = edge_weight (f32, unused)
    const float* W0 = (const float*)d_in[3];
    const float* b0 = (const float*)d_in[4];
    const float* W1 = (const float*)d_in[5];
    const float* b1 = (const float*)d_in[6];
    const float* W2 = (const float*)d_in[7];
    const float* b2 = (const float*)d_in[8];
    float* out = (float*)d_out;

    int n_nodes = in_sizes[0] / N_IN;  // 1,000,000
    dim3 block(256);
    dim3 grid((n_nodes + block.x - 1) / block.x);
    gnn_mlp_kernel<<<grid, block, 0, stream>>>(x, W0, b0, W1, b1, W2, b2, out, n_nodes);
}

// Round 2
// 140.288 us; speedup vs baseline: 1.8813x; 1.8813x over previous
//
#include <hip/hip_runtime.h>

// Fused 3-layer MLP via MFMA with split-bf16 (hi+lo) 3-term products:
//   out = relu(relu(x@W0+b0)@W1+b1)@W2+b2
// x: [N,128] f32, W0:[128,32], W1:[32,32], W2:[32,16], out:[N,16] f32.
// edge_index/edge_weight unused (ChebConv K=1).
//
// Each wave computes a 16-node tile with v_mfma_f32_16x16x32_bf16.
// A-frag: lane l holds A[l&15][8*(l>>4)+j], j=0..7.
// B-frag: lane l holds B[8*(l>>4)+j][l&15].
// C/D:    lane l holds D[4*(l>>4)+i][l&15], i=0..3 (m89-verified layout).
// Split-bf16: v ~= hi + lo (both bf16); product = ah*bh + al*bh + ah*bl
// recovers ~f32 accuracy (missing lo*lo term ~2^-18 relative).
// Weights are pre-split into fragment-ordered bf16 hi/lo arrays in d_ws.

#define N_IN  128
#define HID   32
#define N_OUT 16

using f32x4  = __attribute__((ext_vector_type(4))) float;
using short8 = __attribute__((ext_vector_type(8))) short;

// chunk layout in ws (each chunk = 64 lanes * 8 bf16 = 512 shorts = 1KB):
//  W0: chunks [0,16): chunk = kc*4 + nh*2 + hl   (kc=0..3, nh=0..1, hl=0..1)
//  W1: chunks [16,20): 16 + nh*2 + hl
//  W2: chunks [20,22): 20 + hl
#define N_CHUNK_SHORTS 512
#define TOTAL_WF_SHORTS (22 * 512)

__device__ __forceinline__ unsigned short f2bf(float f) {
    union { float f; unsigned int u; } v; v.f = f;
    unsigned int u = v.u;
    unsigned int r = (u + 0x7fffu + ((u >> 16) & 1u)) >> 16;  // RNE
    return (unsigned short)r;
}
__device__ __forceinline__ float bf2f(unsigned short b) {
    union { unsigned int u; float f; } v; v.u = ((unsigned int)b) << 16;
    return v.f;
}

__global__ void split_weights(const float* __restrict__ W0,
                              const float* __restrict__ W1,
                              const float* __restrict__ W2,
                              unsigned short* __restrict__ wf) {
    int idx = blockIdx.x * blockDim.x + threadIdx.x;
    if (idx >= TOTAL_WF_SHORTS) return;
    int chunk  = idx >> 9;
    int within = idx & 511;
    int lane = within >> 3;
    int j    = within & 7;
    const float* W; int ncol, k, col, hl;
    if (chunk < 16) {
        int kc = chunk >> 2, nh = (chunk >> 1) & 1; hl = chunk & 1;
        k = kc * 32 + 8 * (lane >> 4) + j; col = nh * 16 + (lane & 15);
        W = W0; ncol = HID;
    } else if (chunk < 20) {
        int c2 = chunk - 16, nh = c2 >> 1; hl = c2 & 1;
        k = 8 * (lane >> 4) + j; col = nh * 16 + (lane & 15);
        W = W1; ncol = HID;
    } else {
        hl = chunk - 20;
        k = 8 * (lane >> 4) + j; col = lane & 15;
        W = W2; ncol = N_OUT;
    }
    float v = W[k * ncol + col];
    unsigned short hi = f2bf(v);
    wf[idx] = (hl == 0) ? hi : f2bf(v - bf2f(hi));
}

#define MFMA3(acc, ah, al, bh, bl)                                          \
    do {                                                                    \
        acc = __builtin_amdgcn_mfma_f32_16x16x32_bf16(ah, bh, acc, 0, 0, 0);\
        acc = __builtin_amdgcn_mfma_f32_16x16x32_bf16(al, bh, acc, 0, 0, 0);\
        acc = __builtin_amdgcn_mfma_f32_16x16x32_bf16(ah, bl, acc, 0, 0, 0);\
    } while (0)

__global__ __launch_bounds__(256) void gnn_mfma(
    const float* __restrict__ x, const unsigned short* __restrict__ wf,
    const float* __restrict__ b0, const float* __restrict__ b1,
    const float* __restrict__ b2, float* __restrict__ out, int n_nodes)
{
    // per-wave transpose buffer: [wave][hl][row 16][col 32 + pad 8]
    __shared__ __align__(16) unsigned short hbuf[4][2][16][40];

    const int tid  = threadIdx.x;
    const int wave = tid >> 6;
    const int l    = tid & 63;
    const int r16  = l & 15;
    const int g    = l >> 4;

    const int nb = (blockIdx.x * 4 + wave) * 16;   // 16 nodes per wave
    if (nb >= n_nodes) return;                      // never taken (1M % 64 == 0)

    const short8* WF = reinterpret_cast<const short8*>(wf);

    const float bc0a = b0[r16], bc0b = b0[16 + r16];
    const float bc1a = b1[r16], bc1b = b1[16 + r16];
    const float bc2  = b2[r16];

    // ---------------- layer 0: h0 = relu(x @ W0 + b0), K=128 ----------------
    f32x4 acc0 = {0.f, 0.f, 0.f, 0.f};
    f32x4 acc1 = {0.f, 0.f, 0.f, 0.f};
    const float* xrow = x + (size_t)(nb + r16) * N_IN + g * 8;

    #pragma unroll
    for (int kc = 0; kc < 4; ++kc) {
        float4 xa = *reinterpret_cast<const float4*>(xrow + kc * 32);
        float4 xb = *reinterpret_cast<const float4*>(xrow + kc * 32 + 4);
        float v[8] = {xa.x, xa.y, xa.z, xa.w, xb.x, xb.y, xb.z, xb.w};
        short8 ah, al;
        #pragma unroll
        for (int j = 0; j < 8; ++j) {
            unsigned short hi = f2bf(v[j]);
            ah[j] = (short)hi;
            al[j] = (short)f2bf(v[j] - bf2f(hi));
        }
        short8 w0h0 = WF[(kc * 4 + 0) * 64 + l];
        short8 w0l0 = WF[(kc * 4 + 1) * 64 + l];
        short8 w0h1 = WF[(kc * 4 + 2) * 64 + l];
        short8 w0l1 = WF[(kc * 4 + 3) * 64 + l];
        MFMA3(acc0, ah, al, w0h0, w0l0);
        MFMA3(acc1, ah, al, w0h1, w0l1);
    }

    // bias + relu, split to bf16 hi/lo, transpose via LDS (C-layout -> A-layout)
    #pragma unroll
    for (int i = 0; i < 4; ++i) {
        int row = 4 * g + i;
        float h = fmaxf(acc0[i] + bc0a, 0.f);
        unsigned short hi = f2bf(h);
        hbuf[wave][0][row][r16] = hi;
        hbuf[wave][1][row][r16] = f2bf(h - bf2f(hi));
        float h2 = fmaxf(acc1[i] + bc0b, 0.f);
        unsigned short hi2 = f2bf(h2);
        hbuf[wave][0][row][16 + r16] = hi2;
        hbuf[wave][1][row][16 + r16] = f2bf(h2 - bf2f(hi2));
    }
    __syncthreads();
    short8 h0h = *reinterpret_cast<const short8*>(&hbuf[wave][0][r16][g * 8]);
    short8 h0l = *reinterpret_cast<const short8*>(&hbuf[wave][1][r16][g * 8]);
    __syncthreads();

    // ---------------- layer 1: h1 = relu(h0 @ W1 + b1), K=32 ----------------
    f32x4 acc2 = {0.f, 0.f, 0.f, 0.f};
    f32x4 acc3 = {0.f, 0.f, 0.f, 0.f};
    {
        short8 w1h0 = WF[(16 + 0) * 64 + l];
        short8 w1l0 = WF[(16 + 1) * 64 + l];
        short8 w1h1 = WF[(16 + 2) * 64 + l];
        short8 w1l1 = WF[(16 + 3) * 64 + l];
        MFMA3(acc2, h0h, h0l, w1h0, w1l0);
        MFMA3(acc3, h0h, h0l, w1h1, w1l1);
    }
    #pragma unroll
    for (int i = 0; i < 4; ++i) {
        int row = 4 * g + i;
        float h = fmaxf(acc2[i] + bc1a, 0.f);
        unsigned short hi = f2bf(h);
        hbuf[wave][0][row][r16] = hi;
        hbuf[wave][1][row][r16] = f2bf(h - bf2f(hi));
        float h2 = fmaxf(acc3[i] + bc1b, 0.f);
        unsigned short hi2 = f2bf(h2);
        hbuf[wave][0][row][16 + r16] = hi2;
        hbuf[wave][1][row][16 + r16] = f2bf(h2 - bf2f(hi2));
    }
    __syncthreads();
    short8 h1h = *reinterpret_cast<const short8*>(&hbuf[wave][0][r16][g * 8]);
    short8 h1l = *reinterpret_cast<const short8*>(&hbuf[wave][1][r16][g * 8]);

    // ---------------- layer 2: o = h1 @ W2 + b2, K=32, N=16 ------------------
    f32x4 accO = {0.f, 0.f, 0.f, 0.f};
    {
        short8 w2h = WF[(20) * 64 + l];
        short8 w2l = WF[(21) * 64 + l];
        MFMA3(accO, h1h, h1l, w2h, w2l);
    }
    #pragma unroll
    for (int i = 0; i < 4; ++i) {
        int row = 4 * g + i;
        out[(size_t)(nb + row) * N_OUT + r16] = accO[i] + bc2;
    }
}

extern "C" void kernel_launch(void* const* d_in, const int* in_sizes, int n_in,
                              void* d_out, int out_size, void* d_ws, size_t ws_size,
                              hipStream_t stream) {
    // setup_inputs() order: x, edge_index, edge_weight, W0, b0, W1, b1, W2, b2
    const float* x  = (const float*)d_in[0];
    const float* W0 = (const float*)d_in[3];
    const float* b0 = (const float*)d_in[4];
    const float* W1 = (const float*)d_in[5];
    const float* b1 = (const float*)d_in[6];
    const float* W2 = (const float*)d_in[7];
    const float* b2 = (const float*)d_in[8];
    float* out = (float*)d_out;
    unsigned short* wf = (unsigned short*)d_ws;   // 22 KB of fragment data

    int n_nodes = in_sizes[0] / N_IN;             // 1,000,000

    split_weights<<<(TOTAL_WF_SHORTS + 255) / 256, 256, 0, stream>>>(W0, W1, W2, wf);

    int nodes_per_block = 64;                      // 4 waves * 16 nodes
    dim3 grid((n_nodes + nodes_per_block - 1) / nodes_per_block);
    gnn_mfma<<<grid, dim3(256), 0, stream>>>(x, wf, b0, b1, b2, out, n_nodes);
}

// Round 3
// 139.919 us; speedup vs baseline: 1.8862x; 1.0026x over previous
//
#include <hip/hip_runtime.h>

// Fused 3-layer MLP via MFMA with split-bf16 (hi+lo) 3-term products:
//   out = relu(relu(x@W0+b0)@W1+b1)@W2+b2
// x: [N,128] f32, W0:[128,32], W1:[32,32], W2:[32,16], out:[N,16] f32.
// edge_index/edge_weight unused (ChebConv K=1).
//
// Each wave computes a 16-node tile with v_mfma_f32_16x16x32_bf16.
// A-frag: lane l holds A[l&15][8*(l>>4)+j], j=0..7.
// B-frag: lane l holds B[8*(l>>4)+j][l&15].
// C/D:    lane l holds D[4*(l>>4)+i][l&15], i=0..3 (m89-verified layout).
// Split: v = hi + lo with hi = TRUNC-to-bf16 (bit mask, exact),
// lo = trunc-bf16(v - hi); product = ah*bh + al*bh + ah*bl (~f32 accuracy).
// Truncation for hi is free (1 AND) and lo compensates the remainder.

#define N_IN  128
#define HID   32
#define N_OUT 16

using f32x4  = __attribute__((ext_vector_type(4))) float;
using short8 = __attribute__((ext_vector_type(8))) short;
using uint4v = __attribute__((ext_vector_type(4))) unsigned int;

// chunk layout in ws (each chunk = 64 lanes * 8 bf16 = 512 shorts = 1KB):
//  W0: chunks [0,16): chunk = kc*4 + nh*2 + hl   (kc=0..3, nh=0..1, hl=0..1)
//  W1: chunks [16,20): 16 + nh*2 + hl
//  W2: chunks [20,22): 20 + hl
#define TOTAL_WF_SHORTS (22 * 512)

__device__ __forceinline__ unsigned fu(float f) {
    union { float f; unsigned u; } v; v.f = f; return v.u;
}
__device__ __forceinline__ float uf(unsigned u) {
    union { unsigned u; float f; } v; v.u = u; return v.f;
}
__device__ __forceinline__ unsigned short f2bf_rne(float f) {
    unsigned u = fu(f);
    return (unsigned short)((u + 0x7fffu + ((u >> 16) & 1u)) >> 16);
}

__global__ void split_weights(const float* __restrict__ W0,
                              const float* __restrict__ W1,
                              const float* __restrict__ W2,
                              unsigned short* __restrict__ wf) {
    int idx = blockIdx.x * blockDim.x + threadIdx.x;
    if (idx >= TOTAL_WF_SHORTS) return;
    int chunk  = idx >> 9;
    int within = idx & 511;
    int lane = within >> 3;
    int j    = within & 7;
    const float* W; int ncol, k, col, hl;
    if (chunk < 16) {
        int kc = chunk >> 2, nh = (chunk >> 1) & 1; hl = chunk & 1;
        k = kc * 32 + 8 * (lane >> 4) + j; col = nh * 16 + (lane & 15);
        W = W0; ncol = HID;
    } else if (chunk < 20) {
        int c2 = chunk - 16, nh = c2 >> 1; hl = c2 & 1;
        k = 8 * (lane >> 4) + j; col = nh * 16 + (lane & 15);
        W = W1; ncol = HID;
    } else {
        hl = chunk - 20;
        k = 8 * (lane >> 4) + j; col = lane & 15;
        W = W2; ncol = N_OUT;
    }
    float v = W[k * ncol + col];
    // hi = truncation (matches device-side split), lo = RNE of remainder
    unsigned hi_bits = fu(v) & 0xFFFF0000u;
    wf[idx] = (hl == 0) ? (unsigned short)(hi_bits >> 16)
                        : f2bf_rne(v - uf(hi_bits));
}

#define MFMA3(acc, ah, al, bh, bl)                                          \
    do {                                                                    \
        acc = __builtin_amdgcn_mfma_f32_16x16x32_bf16(ah, bh, acc, 0, 0, 0);\
        acc = __builtin_amdgcn_mfma_f32_16x16x32_bf16(al, bh, acc, 0, 0, 0);\
        acc = __builtin_amdgcn_mfma_f32_16x16x32_bf16(ah, bl, acc, 0, 0, 0);\
    } while (0)

__global__ __launch_bounds__(256, 4) void gnn_mfma(
    const float* __restrict__ x, const unsigned short* __restrict__ wf,
    const float* __restrict__ b0, const float* __restrict__ b1,
    const float* __restrict__ b2, float* __restrict__ out, int n_nodes)
{
    // per-wave transpose buffers, ping-pong: [wave][buf][hl][row 16][col 32+pad 8]
    __shared__ __align__(16) unsigned short hbuf[4][2][2][16][40];

    const int tid  = threadIdx.x;
    const int wave = tid >> 6;
    const int l    = tid & 63;
    const int r16  = l & 15;
    const int g    = l >> 4;

    const int nb = (blockIdx.x * 4 + wave) * 16;   // 16 nodes per wave
    if (nb >= n_nodes) return;                      // never taken (1M % 64 == 0)

    const short8* WF = reinterpret_cast<const short8*>(wf);

    const float bc0a = b0[r16], bc0b = b0[16 + r16];
    const float bc1a = b1[r16], bc1b = b1[16 + r16];
    const float bc2  = b2[r16];

    // ---------------- layer 0: h0 = relu(x @ W0 + b0), K=128 ----------------
    f32x4 acc0 = {0.f, 0.f, 0.f, 0.f};
    f32x4 acc1 = {0.f, 0.f, 0.f, 0.f};
    const float* xrow = x + (size_t)(nb + r16) * N_IN + g * 8;

    #pragma unroll
    for (int kc = 0; kc < 4; ++kc) {
        float4 xa = *reinterpret_cast<const float4*>(xrow + kc * 32);
        float4 xb = *reinterpret_cast<const float4*>(xrow + kc * 32 + 4);
        float f[8] = {xa.x, xa.y, xa.z, xa.w, xb.x, xb.y, xb.z, xb.w};
        uint4v hv, lv;
        #pragma unroll
        for (int p = 0; p < 4; ++p) {
            unsigned u0 = fu(f[2 * p]), u1 = fu(f[2 * p + 1]);
            unsigned h0b = u0 & 0xFFFF0000u, h1b = u1 & 0xFFFF0000u;
            hv[p] = h1b | (u0 >> 16);
            float l0 = f[2 * p] - uf(h0b), l1 = f[2 * p + 1] - uf(h1b);
            lv[p] = (fu(l1) & 0xFFFF0000u) | (fu(l0) >> 16);
        }
        short8 ah = __builtin_bit_cast(short8, hv);
        short8 al = __builtin_bit_cast(short8, lv);
        short8 w0h0 = WF[(kc * 4 + 0) * 64 + l];
        short8 w0l0 = WF[(kc * 4 + 1) * 64 + l];
        short8 w0h1 = WF[(kc * 4 + 2) * 64 + l];
        short8 w0l1 = WF[(kc * 4 + 3) * 64 + l];
        MFMA3(acc0, ah, al, w0h0, w0l0);
        MFMA3(acc1, ah, al, w0h1, w0l1);
    }

    // bias + relu, split hi/lo (truncation), transpose via LDS buf0
    #pragma unroll
    for (int i = 0; i < 4; ++i) {
        int row = 4 * g + i;
        float h = fmaxf(acc0[i] + bc0a, 0.f);
        unsigned hb = fu(h) & 0xFFFF0000u;
        hbuf[wave][0][0][row][r16] = (unsigned short)(hb >> 16);
        hbuf[wave][0][1][row][r16] = (unsigned short)(fu(h - uf(hb)) >> 16);
        float h2 = fmaxf(acc1[i] + bc0b, 0.f);
        unsigned hb2 = fu(h2) & 0xFFFF0000u;
        hbuf[wave][0][0][row][16 + r16] = (unsigned short)(hb2 >> 16);
        hbuf[wave][0][1][row][16 + r16] = (unsigned short)(fu(h2 - uf(hb2)) >> 16);
    }
    __syncthreads();
    short8 h0h = *reinterpret_cast<const short8*>(&hbuf[wave][0][0][r16][g * 8]);
    short8 h0l = *reinterpret_cast<const short8*>(&hbuf[wave][0][1][r16][g * 8]);

    // ---------------- layer 1: h1 = relu(h0 @ W1 + b1), K=32 ----------------
    f32x4 acc2 = {0.f, 0.f, 0.f, 0.f};
    f32x4 acc3 = {0.f, 0.f, 0.f, 0.f};
    {
        short8 w1h0 = WF[(16 + 0) * 64 + l];
        short8 w1l0 = WF[(16 + 1) * 64 + l];
        short8 w1h1 = WF[(16 + 2) * 64 + l];
        short8 w1l1 = WF[(16 + 3) * 64 + l];
        MFMA3(acc2, h0h, h0l, w1h0, w1l0);
        MFMA3(acc3, h0h, h0l, w1h1, w1l1);
    }
    #pragma unroll
    for (int i = 0; i < 4; ++i) {
        int row = 4 * g + i;
        float h = fmaxf(acc2[i] + bc1a, 0.f);
        unsigned hb = fu(h) & 0xFFFF0000u;
        hbuf[wave][1][0][row][r16] = (unsigned short)(hb >> 16);
        hbuf[wave][1][1][row][r16] = (unsigned short)(fu(h - uf(hb)) >> 16);
        float h2 = fmaxf(acc3[i] + bc1b, 0.f);
        unsigned hb2 = fu(h2) & 0xFFFF0000u;
        hbuf[wave][1][0][row][16 + r16] = (unsigned short)(hb2 >> 16);
        hbuf[wave][1][1][row][16 + r16] = (unsigned short)(fu(h2 - uf(hb2)) >> 16);
    }
    __syncthreads();
    short8 h1h = *reinterpret_cast<const short8*>(&hbuf[wave][1][0][r16][g * 8]);
    short8 h1l = *reinterpret_cast<const short8*>(&hbuf[wave][1][1][r16][g * 8]);

    // ---------------- layer 2: o = h1 @ W2 + b2, K=32, N=16 ------------------
    f32x4 accO = {0.f, 0.f, 0.f, 0.f};
    {
        short8 w2h = WF[(20) * 64 + l];
        short8 w2l = WF[(21) * 64 + l];
        MFMA3(accO, h1h, h1l, w2h, w2l);
    }
    #pragma unroll
    for (int i = 0; i < 4; ++i) {
        int row = 4 * g + i;
        out[(size_t)(nb + row) * N_OUT + r16] = accO[i] + bc2;
    }
}

extern "C" void kernel_launch(void* const* d_in, const int* in_sizes, int n_in,
                              void* d_out, int out_size, void* d_ws, size_t ws_size,
                              hipStream_t stream) {
    // setup_inputs() order: x, edge_index, edge_weight, W0, b0, W1, b1, W2, b2
    const float* x  = (const float*)d_in[0];
    const float* W0 = (const float*)d_in[3];
    const float* b0 = (const float*)d_in[4];
    const float* W1 = (const float*)d_in[5];
    const float* b1 = (const float*)d_in[6];
    const float* W2 = (const float*)d_in[7];
    const float* b2 = (const float*)d_in[8];
    float* out = (float*)d_out;
    unsigned short* wf = (unsigned short*)d_ws;   // 22 KB of fragment data

    int n_nodes = in_sizes[0] / N_IN;             // 1,000,000

    split_weights<<<(TOTAL_WF_SHORTS + 255) / 256, 256, 0, stream>>>(W0, W1, W2, wf);

    int nodes_per_block = 64;                      // 4 waves * 16 nodes
    dim3 grid((n_nodes + nodes_per_block - 1) / nodes_per_block);
    gnn_mfma<<<grid, dim3(256), 0, stream>>>(x, wf, b0, b1, b2, out, n_nodes);
}

// Round 4
// 118.420 us; speedup vs baseline: 2.2287x; 1.1816x over previous
//
#include <hip/hip_runtime.h>

// Fused 3-layer MLP via MFMA with split-bf16 (hi+lo) 3-term products:
//   out = relu(relu(x@W0+b0)@W1+b1)@W2+b2
// x: [N,128] f32, W0:[128,32], W1:[32,32], W2:[32,16], out:[N,16] f32.
// edge_index/edge_weight unused (ChebConv K=1).
//
// R3 structure: persistent grid (4 blocks/CU), weights staged once per block
// into LDS (per-tile fragment loads become ds_read_b128, off the VMEM/TA
// path), and a barrier-free main loop (hbuf is wave-private; the only
// __syncthreads is after weight staging). Per-tile VMEM: 30 -> 8 instrs.
//
// MFMA frag layouts (m89-verified):
//  A: lane l holds A[l&15][8*(l>>4)+j], j=0..7
//  B: lane l holds B[8*(l>>4)+j][l&15]
//  C/D: lane l holds D[4*(l>>4)+i][l&15], i=0..3
// Split: v = hi + lo, hi = trunc-to-bf16 (bit mask, exact),
// lo = rne-bf16(v - hi); product = ah*bh + al*bh + ah*bl (~f32 accuracy).

#define N_IN  128
#define HID   32
#define N_OUT 16

using f32x4  = __attribute__((ext_vector_type(4))) float;
using short8 = __attribute__((ext_vector_type(8))) short;
using uint4v = __attribute__((ext_vector_type(4))) unsigned int;

// chunk layout (each chunk = 64 lanes * 8 bf16 = 512 shorts = 1KB):
//  W0: chunks [0,16): chunk = kc*4 + nh*2 + hl   (kc=0..3, nh=0..1, hl=0..1)
//  W1: chunks [16,20): 16 + nh*2 + hl
//  W2: chunks [20,22): 20 + hl
#define N_CHUNKS 22
#define TOTAL_WF_SHORTS (N_CHUNKS * 512)
#define WLDS_GRANULES (N_CHUNKS * 64)   // 16B granules

__device__ __forceinline__ unsigned fu(float f) {
    union { float f; unsigned u; } v; v.f = f; return v.u;
}
__device__ __forceinline__ float uf(unsigned u) {
    union { unsigned u; float f; } v; v.u = u; return v.f;
}
__device__ __forceinline__ unsigned short f2bf_rne(float f) {
    unsigned u = fu(f);
    return (unsigned short)((u + 0x7fffu + ((u >> 16) & 1u)) >> 16);
}

__global__ void split_weights(const float* __restrict__ W0,
                              const float* __restrict__ W1,
                              const float* __restrict__ W2,
                              unsigned short* __restrict__ wf) {
    int idx = blockIdx.x * blockDim.x + threadIdx.x;
    if (idx >= TOTAL_WF_SHORTS) return;
    int chunk  = idx >> 9;
    int within = idx & 511;
    int lane = within >> 3;
    int j    = within & 7;
    const float* W; int ncol, k, col, hl;
    if (chunk < 16) {
        int kc = chunk >> 2, nh = (chunk >> 1) & 1; hl = chunk & 1;
        k = kc * 32 + 8 * (lane >> 4) + j; col = nh * 16 + (lane & 15);
        W = W0; ncol = HID;
    } else if (chunk < 20) {
        int c2 = chunk - 16, nh = c2 >> 1; hl = c2 & 1;
        k = 8 * (lane >> 4) + j; col = nh * 16 + (lane & 15);
        W = W1; ncol = HID;
    } else {
        hl = chunk - 20;
        k = 8 * (lane >> 4) + j; col = lane & 15;
        W = W2; ncol = N_OUT;
    }
    float v = W[k * ncol + col];
    unsigned hi_bits = fu(v) & 0xFFFF0000u;
    wf[idx] = (hl == 0) ? (unsigned short)(hi_bits >> 16)
                        : f2bf_rne(v - uf(hi_bits));
}

#define MFMA3(acc, ah, al, bh, bl)                                          \
    do {                                                                    \
        acc = __builtin_amdgcn_mfma_f32_16x16x32_bf16(ah, bh, acc, 0, 0, 0);\
        acc = __builtin_amdgcn_mfma_f32_16x16x32_bf16(al, bh, acc, 0, 0, 0);\
        acc = __builtin_amdgcn_mfma_f32_16x16x32_bf16(ah, bl, acc, 0, 0, 0);\
    } while (0)

__global__ __launch_bounds__(256, 4) void gnn_mfma(
    const float* __restrict__ x, const unsigned short* __restrict__ wf,
    const float* __restrict__ b0, const float* __restrict__ b1,
    const float* __restrict__ b2, float* __restrict__ out,
    int n_tiles, int n_waves_total)
{
    __shared__ __align__(16) unsigned short wlds[N_CHUNKS * 512];  // 22 KB
    // wave-private transpose buffer: [wave][hl][row 16][col 32 + pad 8]
    __shared__ __align__(16) unsigned short hbuf[4][2][16][40];    // 10.25 KB

    const int tid  = threadIdx.x;
    const int wave = tid >> 6;
    const int l    = tid & 63;
    const int r16  = l & 15;
    const int g    = l >> 4;

    // ---- stage weight fragments into LDS once per block ----
    {
        const uint4v* wfv = reinterpret_cast<const uint4v*>(wf);
        uint4v* wl = reinterpret_cast<uint4v*>(wlds);
        for (int gg = tid; gg < WLDS_GRANULES; gg += 256)
            wl[gg] = wfv[gg];
    }
    __syncthreads();   // the only block-wide barrier

    const short8* WL = reinterpret_cast<const short8*>(wlds);

    const float bc0a = b0[r16], bc0b = b0[16 + r16];
    const float bc1a = b1[r16], bc1b = b1[16 + r16];
    const float bc2  = b2[r16];

    const int gw = blockIdx.x * 4 + wave;   // global wave id

    for (int tile = gw; tile < n_tiles; tile += n_waves_total) {
        const int nb = tile * 16;

        // -------- layer 0: h0 = relu(x @ W0 + b0), K=128 --------
        f32x4 acc0 = {0.f, 0.f, 0.f, 0.f};
        f32x4 acc1 = {0.f, 0.f, 0.f, 0.f};
        const float* xrow = x + (size_t)(nb + r16) * N_IN + g * 8;

        #pragma unroll
        for (int kc = 0; kc < 4; ++kc) {
            float4 xa = *reinterpret_cast<const float4*>(xrow + kc * 32);
            float4 xb = *reinterpret_cast<const float4*>(xrow + kc * 32 + 4);
            float f[8] = {xa.x, xa.y, xa.z, xa.w, xb.x, xb.y, xb.z, xb.w};
            uint4v hv, lv;
            #pragma unroll
            for (int p = 0; p < 4; ++p) {
                unsigned u0 = fu(f[2 * p]), u1 = fu(f[2 * p + 1]);
                unsigned h0b = u0 & 0xFFFF0000u, h1b = u1 & 0xFFFF0000u;
                hv[p] = h1b | (u0 >> 16);
                float l0 = f[2 * p] - uf(h0b), l1 = f[2 * p + 1] - uf(h1b);
                lv[p] = (fu(l1) & 0xFFFF0000u) | (fu(l0) >> 16);
            }
            short8 ah = __builtin_bit_cast(short8, hv);
            short8 al = __builtin_bit_cast(short8, lv);
            short8 w0h0 = WL[(kc * 4 + 0) * 64 + l];
            short8 w0l0 = WL[(kc * 4 + 1) * 64 + l];
            short8 w0h1 = WL[(kc * 4 + 2) * 64 + l];
            short8 w0l1 = WL[(kc * 4 + 3) * 64 + l];
            MFMA3(acc0, ah, al, w0h0, w0l0);
            MFMA3(acc1, ah, al, w0h1, w0l1);
        }

        // bias + relu, split hi/lo, wave-private LDS transpose (no barrier)
        #pragma unroll
        for (int i = 0; i < 4; ++i) {
            int row = 4 * g + i;
            float h = fmaxf(acc0[i] + bc0a, 0.f);
            unsigned hb = fu(h) & 0xFFFF0000u;
            hbuf[wave][0][row][r16] = (unsigned short)(hb >> 16);
            hbuf[wave][1][row][r16] = (unsigned short)(fu(h - uf(hb)) >> 16);
            float h2 = fmaxf(acc1[i] + bc0b, 0.f);
            unsigned hb2 = fu(h2) & 0xFFFF0000u;
            hbuf[wave][0][row][16 + r16] = (unsigned short)(hb2 >> 16);
            hbuf[wave][1][row][16 + r16] = (unsigned short)(fu(h2 - uf(hb2)) >> 16);
        }
        short8 h0h = *reinterpret_cast<const short8*>(&hbuf[wave][0][r16][g * 8]);
        short8 h0l = *reinterpret_cast<const short8*>(&hbuf[wave][1][r16][g * 8]);

        // -------- layer 1: h1 = relu(h0 @ W1 + b1), K=32 --------
        f32x4 acc2 = {0.f, 0.f, 0.f, 0.f};
        f32x4 acc3 = {0.f, 0.f, 0.f, 0.f};
        {
            short8 w1h0 = WL[(16 + 0) * 64 + l];
            short8 w1l0 = WL[(16 + 1) * 64 + l];
            short8 w1h1 = WL[(16 + 2) * 64 + l];
            short8 w1l1 = WL[(16 + 3) * 64 + l];
            MFMA3(acc2, h0h, h0l, w1h0, w1l0);
            MFMA3(acc3, h0h, h0l, w1h1, w1l1);
        }
        #pragma unroll
        for (int i = 0; i < 4; ++i) {
            int row = 4 * g + i;
            float h = fmaxf(acc2[i] + bc1a, 0.f);
            unsigned hb = fu(h) & 0xFFFF0000u;
            hbuf[wave][0][row][r16] = (unsigned short)(hb >> 16);
            hbuf[wave][1][row][r16] = (unsigned short)(fu(h - uf(hb)) >> 16);
            float h2 = fmaxf(acc3[i] + bc1b, 0.f);
            unsigned hb2 = fu(h2) & 0xFFFF0000u;
            hbuf[wave][0][row][16 + r16] = (unsigned short)(hb2 >> 16);
            hbuf[wave][1][row][16 + r16] = (unsigned short)(fu(h2 - uf(hb2)) >> 16);
        }
        short8 h1h = *reinterpret_cast<const short8*>(&hbuf[wave][0][r16][g * 8]);
        short8 h1l = *reinterpret_cast<const short8*>(&hbuf[wave][1][r16][g * 8]);

        // -------- layer 2: o = h1 @ W2 + b2, K=32, N=16 --------
        f32x4 accO = {0.f, 0.f, 0.f, 0.f};
        {
            short8 w2h = WL[(20) * 64 + l];
            short8 w2l = WL[(21) * 64 + l];
            MFMA3(accO, h1h, h1l, w2h, w2l);
        }
        #pragma unroll
        for (int i = 0; i < 4; ++i) {
            int row = 4 * g + i;
            out[(size_t)(nb + row) * N_OUT + r16] = accO[i] + bc2;
        }
    }
}

extern "C" void kernel_launch(void* const* d_in, const int* in_sizes, int n_in,
                              void* d_out, int out_size, void* d_ws, size_t ws_size,
                              hipStream_t stream) {
    // setup_inputs() order: x, edge_index, edge_weight, W0, b0, W1, b1, W2, b2
    const float* x  = (const float*)d_in[0];
    const float* W0 = (const float*)d_in[3];
    const float* b0 = (const float*)d_in[4];
    const float* W1 = (const float*)d_in[5];
    const float* b1 = (const float*)d_in[6];
    const float* W2 = (const float*)d_in[7];
    const float* b2 = (const float*)d_in[8];
    float* out = (float*)d_out;
    unsigned short* wf = (unsigned short*)d_ws;   // 22 KB of fragment data

    int n_nodes = in_sizes[0] / N_IN;             // 1,000,000
    int n_tiles = n_nodes / 16;                   // 62,500 (exact)

    split_weights<<<(TOTAL_WF_SHORTS + 255) / 256, 256, 0, stream>>>(W0, W1, W2, wf);

    const int n_blocks = 1024;                    // 4 blocks/CU persistent
    const int n_waves_total = n_blocks * 4;
    gnn_mfma<<<dim3(n_blocks), dim3(256), 0, stream>>>(
        x, wf, b0, b1, b2, out, n_tiles, n_waves_total);
}